// Round 2
// baseline (304.206 us; speedup 1.0000x reference)
//
#include <hip/hip_runtime.h>
#include <hip/hip_bf16.h>
#include <stdint.h>

#define NB 64
#define NA 33600
#define NK 500
#define HW3 25600
#define HW4 6400
#define HW5 1600
#define OFF4 25600
#define OFF5 32000
#define NBIN 2048
#define CAP 2048

typedef unsigned int u32;
typedef unsigned long long u64;

__device__ __forceinline__ float sigf(float x) { return 1.0f / (1.0f + expf(-x)); }

__device__ __forceinline__ u32 f2key(float f) {
  u32 u = __float_as_uint(f);
  return (u & 0x80000000u) ? ~u : (u | 0x80000000u);
}
__device__ __forceinline__ float key2f(u32 k) {
  u32 u = (k & 0x80000000u) ? (k ^ 0x80000000u) : ~k;
  return __uint_as_float(u);
}
__device__ __forceinline__ int bin_of(float s) {
  int b = (int)(s * 2048.0f);
  return b > 2047 ? 2047 : b;   // monotone nondecreasing in s
}

// ---------------- K1: masked max-score -> key + per-batch histogram ----------
__global__ __launch_bounds__(256) void k_score(
    const float* __restrict__ cls3, const float* __restrict__ obj3,
    const float* __restrict__ cls4, const float* __restrict__ obj4,
    const float* __restrict__ cls5, const float* __restrict__ obj5,
    u32* __restrict__ keys, u32* __restrict__ ghist)
{
  int t = blockIdx.x * 256 + threadIdx.x;
  if (t >= NB * NA) return;
  int b = t / NA;
  int a = t - b * NA;
  const float* cls; const float* obj; int pos, HW;
  if (a < OFF4)      { cls = cls3; obj = obj3; pos = a;        HW = HW3; }
  else if (a < OFF5) { cls = cls4; obj = obj4; pos = a - OFF4; HW = HW4; }
  else               { cls = cls5; obj = obj5; pos = a - OFF5; HW = HW5; }
  float so = sigf(obj[b * HW + pos]);
  float s0 = so * sigf(cls[(b * 2) * HW + pos]);
  float s1 = so * sigf(cls[(b * 2 + 1) * HW + pos]);
  float s  = fmaxf(s0, s1);
  float masked = (s > 0.3f) ? s : -1.0f;
  keys[t] = f2key(masked);
  if (s > 0.3f) atomicAdd(&ghist[b * NBIN + bin_of(s)], 1u);
}

// ---------------- K2a: find pivot bin (max p with suffix(p) >= 500) ----------
__global__ __launch_bounds__(256) void k_pivot(
    const u32* __restrict__ ghist, int* __restrict__ pivot, int* __restrict__ ok)
{
  int b = blockIdx.x, t = threadIdx.x;
  __shared__ u32 hb[NBIN];
  __shared__ u32 part[256];
  const u32* h = ghist + b * NBIN;
  for (int i = t; i < NBIN; i += 256) hb[i] = h[i];
  __syncthreads();
  u32 s = 0;
#pragma unroll
  for (int k = 0; k < 8; ++k) s += hb[t * 8 + k];
  part[t] = s;
  __syncthreads();
  for (int off = 1; off < 256; off <<= 1) {
    u32 add = (t + off < 256) ? part[t + off] : 0u;
    __syncthreads();
    part[t] += add;
    __syncthreads();
  }
  u32 S = part[t];
  u32 Snext = (t == 255) ? 0u : part[t + 1];
  if (t == 0) { ok[b] = (part[0] >= NK) ? 1 : 0; if (part[0] < NK) pivot[b] = NBIN; }
  if (S >= NK && Snext < NK) {
    u32 run = Snext;
    int p = 0;
    for (int k = 7; k >= 0; --k) {
      run += hb[t * 8 + k];
      if (run >= NK) { p = t * 8 + k; break; }
    }
    pivot[b] = p;
  }
}

// ---------------- K2b: collect candidates (bin >= pivot) ---------------------
__global__ __launch_bounds__(256) void k_collect(
    const u32* __restrict__ keys, const int* __restrict__ pivot, const int* __restrict__ ok,
    u64* __restrict__ cand, u32* __restrict__ cnt)
{
  int blk = blockIdx.x;
  int b = blk >> 2, seg = blk & 3;
  if (!ok[b]) return;
  int p = pivot[b];
  const uint4* kb4 = reinterpret_cast<const uint4*>(keys + (size_t)b * NA);
  int base4 = seg * 2100;               // NA/4/4segs
  for (int i4 = base4 + threadIdx.x; i4 < base4 + 2100; i4 += 256) {
    uint4 kv = kb4[i4];
    u32 ks[4] = {kv.x, kv.y, kv.z, kv.w};
#pragma unroll
    for (int c = 0; c < 4; ++c) {
      float s = key2f(ks[c]);
      if (s > 0.3f && bin_of(s) >= p) {
        u32 slot = atomicAdd(&cnt[b], 1u);
        if (slot < CAP)
          cand[(size_t)b * CAP + slot] = ((u64)ks[c] << 16) | (u32)(0xFFFF - (i4 * 4 + c));
      }
    }
  }
}

// ---------------- K2c: exact rank of candidates -> ordered top-500 -----------
__global__ __launch_bounds__(1024) void k_rank(
    const u64* __restrict__ cand, const u32* __restrict__ cnt, int* __restrict__ ok,
    int* __restrict__ top_idx, float* __restrict__ top_score)
{
  int b = blockIdx.x;
  if (!ok[b]) return;
  u32 n = cnt[b];
  if (n > CAP) { if (threadIdx.x == 0) ok[b] = 0; return; }
  __shared__ u64 coll[CAP];
  for (u32 i = threadIdx.x; i < n; i += 1024) coll[i] = cand[(size_t)b * CAP + i];
  __syncthreads();
  for (u32 t = threadIdx.x; t < n; t += 1024) {
    u64 k = coll[t];
    int rank = 0;
    for (u32 j = 0; j < n; ++j) rank += (coll[j] > k) ? 1 : 0;
    if (rank < NK) {
      top_idx[b * NK + rank]   = 0xFFFF - (int)(k & 0xFFFFull);
      top_score[b * NK + rank] = key2f((u32)(k >> 16));
    }
  }
}

// ---------------- K2-fallback: exact 48-bit radix select (rare path) ---------
__global__ __launch_bounds__(1024) void k_select_fb(
    const u32* __restrict__ keys, const int* __restrict__ ok,
    int* __restrict__ top_idx, float* __restrict__ top_score)
{
  int b = blockIdx.x;
  if (ok[b]) return;
  int tid = threadIdx.x;
  __shared__ u32 hist[256];
  __shared__ u32 suf[256];
  __shared__ u64 coll[512];
  __shared__ u32 sh_R;
  __shared__ int sh_digit;
  __shared__ u32 sh_cnt;
  const u32* kb = keys + (size_t)b * NA;
  if (tid == 0) sh_cnt = 0;

  u64 prefix = 0, prefmask = 0;
  u32 R = NK;
  for (int pass = 0; pass < 6; ++pass) {
    int shift = 40 - 8 * pass;
    if (tid < 256) hist[tid] = 0;
    __syncthreads();
    for (int i = tid; i < NA; i += 1024) {
      u64 k48 = ((u64)kb[i] << 16) | (u32)(0xFFFF - i);
      if ((k48 & prefmask) == prefix)
        atomicAdd(&hist[(u32)(k48 >> shift) & 255u], 1u);
    }
    __syncthreads();
    if (tid < 256) suf[tid] = hist[tid];
    __syncthreads();
    for (int off = 1; off < 256; off <<= 1) {
      u32 add = 0;
      if (tid < 256 && tid + off < 256) add = suf[tid + off];
      __syncthreads();
      if (tid < 256) suf[tid] += add;
      __syncthreads();
    }
    if (tid < 256) {
      u32 s = suf[tid];
      u32 snext = (tid == 255) ? 0u : suf[tid + 1];
      if (s >= R && snext < R) { sh_digit = tid; sh_R = R - snext; }
    }
    __syncthreads();
    int dsel = sh_digit;
    R = sh_R;
    prefix |= ((u64)dsel) << shift;
    prefmask |= 0xFFull << shift;
    __syncthreads();
  }

  for (int i = tid; i < NA; i += 1024) {
    u64 k48 = ((u64)kb[i] << 16) | (u32)(0xFFFF - i);
    if (k48 >= prefix) {
      u32 slot = atomicAdd(&sh_cnt, 1u);
      if (slot < 512) coll[slot] = k48;
    }
  }
  __syncthreads();
  int n = (sh_cnt < (u32)NK) ? (int)sh_cnt : NK;
  if (tid < NK) { top_idx[b * NK + tid] = 0; top_score[b * NK + tid] = -1.0f; }
  __syncthreads();
  for (int t = tid; t < n; t += 1024) {
    u64 k = coll[t];
    int rank = 0;
    for (int j = 0; j < n; ++j) rank += (coll[j] > k) ? 1 : 0;
    int idx = 0xFFFF - (int)(k & 0xFFFFull);
    top_idx[b * NK + rank] = idx;
    top_score[b * NK + rank] = key2f((u32)(k >> 16));
  }
}

// ---------------- K3: decode boxes + labels for selected anchors -------------
__global__ __launch_bounds__(256) void k_decode(
    const int* __restrict__ top_idx,
    const float* __restrict__ cls3, const float* __restrict__ obj3, const float* __restrict__ reg3,
    const float* __restrict__ cls4, const float* __restrict__ obj4, const float* __restrict__ reg4,
    const float* __restrict__ cls5, const float* __restrict__ obj5, const float* __restrict__ reg5,
    float4* __restrict__ boxes, float4* __restrict__ boxesoff,
    float* __restrict__ out_labels)
{
  int t = blockIdx.x * 256 + threadIdx.x;
  if (t >= NB * NK) return;
  int b = t / NK;
  int a = top_idx[t];
  const float *cls, *obj, *reg; int pos, HW, x, y; float stride;
  if (a < OFF4) {
    cls = cls3; obj = obj3; reg = reg3; pos = a; HW = HW3; stride = 8.0f;
    y = pos / 160; x = pos - y * 160;
  } else if (a < OFF5) {
    cls = cls4; obj = obj4; reg = reg4; pos = a - OFF4; HW = HW4; stride = 16.0f;
    y = pos / 80; x = pos - y * 80;
  } else {
    cls = cls5; obj = obj5; reg = reg5; pos = a - OFF5; HW = HW5; stride = 32.0f;
    y = pos / 40; x = pos - y * 40;
  }
  float dx = reg[(b * 4 + 0) * HW + pos];
  float dy = reg[(b * 4 + 1) * HW + pos];
  float dw = reg[(b * 4 + 2) * HW + pos];
  float dh = reg[(b * 4 + 3) * HW + pos];
  float cx = ((float)x + sigf(dx)) * stride;
  float cy = ((float)y + sigf(dy)) * stride;
  float w = expf(dw) * stride;
  float h = expf(dh) * stride;
  float x1 = cx - w * 0.5f, y1 = cy - h * 0.5f;
  float x2 = cx + w * 0.5f, y2 = cy + h * 0.5f;
  float so = sigf(obj[b * HW + pos]);
  float s0 = so * sigf(cls[(b * 2) * HW + pos]);
  float s1 = so * sigf(cls[(b * 2 + 1) * HW + pos]);
  int label = (s1 > s0) ? 1 : 0;
  float off = (float)label * 10000.0f;
  boxes[t]    = make_float4(x1, y1, x2, y2);
  boxesoff[t] = make_float4(x1 + off, y1 + off, x2 + off, y2 + off);
  out_labels[t] = (float)label;
}

// ---------------- K4: suppression bit-matrix (iou >= 0.5) --------------------
__global__ __launch_bounds__(256) void k_iou(
    const float4* __restrict__ boxesoff, u64* __restrict__ mask)
{
  int t = blockIdx.x * 256 + threadIdx.x;
  if (t >= NB * NK * 8) return;
  int w = t & 7;
  int bi = t >> 3;
  int b = bi / NK;
  float4 A = boxesoff[bi];
  float areaA = (A.z - A.x) * (A.w - A.y);
  const float4* base = boxesoff + b * NK;
  int j0 = w * 64;
  int jmax = (NK - j0 < 64) ? (NK - j0) : 64;
  u64 bits = 0;
  for (int jj = 0; jj < jmax; ++jj) {
    float4 Bx = base[j0 + jj];
    float areaB = (Bx.z - Bx.x) * (Bx.w - Bx.y);
    float ix1 = fmaxf(A.x, Bx.x);
    float iy1 = fmaxf(A.y, Bx.y);
    float ix2 = fminf(A.z, Bx.z);
    float iy2 = fminf(A.w, Bx.w);
    float iw = fmaxf(ix2 - ix1, 0.0f);
    float ih = fmaxf(iy2 - iy1, 0.0f);
    float inter = iw * ih;
    float uni = areaA + areaB - inter;
    float iou = inter / (uni + 1e-7f);
    bits |= ((u64)(iou >= 0.5f)) << jj;
  }
  mask[t] = bits;
}

// ---------------- K5: sequential greedy NMS scan + finalize ------------------
__global__ __launch_bounds__(64) void k_nms(
    const u64* __restrict__ mask, const float* __restrict__ top_score,
    const float4* __restrict__ boxes,
    float* __restrict__ out_boxes, float* __restrict__ out_scores,
    float* __restrict__ out_keep)
{
  __shared__ __align__(16) u64 m[504 * 8];
  int b = blockIdx.x;
  int lane = threadIdx.x;
  const u64* mb = mask + (size_t)b * (NK * 8);
  for (int i = lane; i < NK * 8; i += 64) m[i] = mb[i];
  if (lane < 32) m[NK * 8 + lane] = 0;

  u64 validw[8];
#pragma unroll
  for (int c = 0; c < 8; ++c) {
    int r = c * 64 + lane;
    float s = (r < NK) ? top_score[b * NK + r] : -1.0f;
    validw[c] = __ballot(s > 0.3f);
  }
  __syncthreads();

  const ulonglong2* m2 = reinterpret_cast<const ulonglong2*>(m);
  u64 supp[8] = {0, 0, 0, 0, 0, 0, 0, 0};
  u64 kw[8]   = {0, 0, 0, 0, 0, 0, 0, 0};

#pragma unroll
  for (int w = 0; w < 8; ++w) {
    const int WP2 = (w & ~1) >> 1;
    const int IMAX = (w == 7) ? 52 : 64;
    ulonglong2 A[4], Bv[4];
#pragma unroll
    for (int p = 0; p < 4; ++p) A[p] = m2[(w * 64 + 0) * 4 + p];
#pragma unroll
    for (int p = 0; p < 4; ++p) Bv[p] = m2[(w * 64 + 1) * 4 + p];
    u64 vw = validw[w];
    for (int ib = 0; ib < IMAX; ib += 2) {
      int i = w * 64 + ib;
      {
        ulonglong2 S[4];
#pragma unroll
        for (int p = 0; p < 4; ++p) S[p] = A[p];
#pragma unroll
        for (int p = 0; p < 4; ++p) if (p >= WP2) A[p] = m2[(i + 2) * 4 + p];
        bool kp = (((vw >> ib) & 1ull) != 0) && (((supp[w] >> ib) & 1ull) == 0);
        if (kp) {
          kw[w] |= (1ull << ib);
#pragma unroll
          for (int p = 0; p < 4; ++p) if (p >= WP2) {
            supp[2 * p]     |= S[p].x;
            supp[2 * p + 1] |= S[p].y;
          }
        }
      }
      {
        int ib1 = ib + 1;
        ulonglong2 S[4];
#pragma unroll
        for (int p = 0; p < 4; ++p) S[p] = Bv[p];
#pragma unroll
        for (int p = 0; p < 4; ++p) if (p >= WP2) Bv[p] = m2[(i + 3) * 4 + p];
        bool kp = (((vw >> ib1) & 1ull) != 0) && (((supp[w] >> ib1) & 1ull) == 0);
        if (kp) {
          kw[w] |= (1ull << ib1);
#pragma unroll
          for (int p = 0; p < 4; ++p) if (p >= WP2) {
            supp[2 * p]     |= S[p].x;
            supp[2 * p + 1] |= S[p].y;
          }
        }
      }
    }
  }

#pragma unroll
  for (int c = 0; c < 8; ++c) {
    int r = c * 64 + lane;
    if (r < NK) {
      int kp = (int)((kw[c] >> lane) & 1ull);
      float4 bx = boxes[b * NK + r];
      float s = top_score[b * NK + r];
      float4 ob;
      ob.x = kp ? bx.x : 0.0f;
      ob.y = kp ? bx.y : 0.0f;
      ob.z = kp ? bx.z : 0.0f;
      ob.w = kp ? bx.w : 0.0f;
      reinterpret_cast<float4*>(out_boxes)[b * NK + r] = ob;
      out_scores[b * NK + r] = kp ? s : 0.0f;
      out_keep[b * NK + r]   = kp ? 1.0f : 0.0f;
    }
  }
}

// ---------------- launcher ---------------------------------------------------
extern "C" void kernel_launch(void* const* d_in, const int* in_sizes, int n_in,
                              void* d_out, int out_size, void* d_ws, size_t ws_size,
                              hipStream_t stream) {
  const float* cls3 = (const float*)d_in[0];
  const float* reg3 = (const float*)d_in[1];
  const float* obj3 = (const float*)d_in[2];
  const float* cls4 = (const float*)d_in[3];
  const float* reg4 = (const float*)d_in[4];
  const float* obj4 = (const float*)d_in[5];
  const float* cls5 = (const float*)d_in[6];
  const float* reg5 = (const float*)d_in[7];
  const float* obj5 = (const float*)d_in[8];

  char* ws = (char*)d_ws;
  u32*    keys      = (u32*)   (ws + 0);          //  8,601,600
  u32*    ghist     = (u32*)   (ws + 8601600);    //    524,288
  u32*    cnt       = (u32*)   (ws + 9125888);    //        256
  int*    pivot     = (int*)   (ws + 9126144);    //        256
  int*    ok        = (int*)   (ws + 9126400);    //        256
  u64*    cand      = (u64*)   (ws + 9126656);    //  1,048,576
  int*    top_idx   = (int*)   (ws + 10175232);   //    128,000
  float*  top_score = (float*) (ws + 10303232);   //    128,000
  float4* boxes     = (float4*)(ws + 10431232);   //    512,000
  float4* boxesoff  = (float4*)(ws + 10943232);   //    512,000
  u64*    mask      = (u64*)   (ws + 11455232);   //  2,048,000  (end ~13.5 MB)

  float* out        = (float*)d_out;
  float* out_boxes  = out;
  float* out_scores = out + 128000;
  float* out_labels = out + 160000;
  float* out_keep   = out + 192000;

  hipMemsetAsync(ghist, 0, 524288 + 256, stream);  // ghist + cnt
  k_score<<<(NB * NA + 255) / 256, 256, 0, stream>>>(cls3, obj3, cls4, obj4, cls5, obj5, keys, ghist);
  k_pivot<<<NB, 256, 0, stream>>>(ghist, pivot, ok);
  k_collect<<<NB * 4, 256, 0, stream>>>(keys, pivot, ok, cand, cnt);
  k_rank<<<NB, 1024, 0, stream>>>(cand, cnt, ok, top_idx, top_score);
  k_select_fb<<<NB, 1024, 0, stream>>>(keys, ok, top_idx, top_score);
  k_decode<<<(NB * NK + 255) / 256, 256, 0, stream>>>(top_idx,
      cls3, obj3, reg3, cls4, obj4, reg4, cls5, obj5, reg5,
      boxes, boxesoff, out_labels);
  k_iou<<<(NB * NK * 8 + 255) / 256, 256, 0, stream>>>(boxesoff, mask);
  k_nms<<<NB, 64, 0, stream>>>(mask, top_score, boxes, out_boxes, out_scores, out_keep);
}

// Round 3
// 214.107 us; speedup vs baseline: 1.4208x; 1.4208x over previous
//
#include <hip/hip_runtime.h>
#include <hip/hip_bf16.h>
#include <stdint.h>

#define NB 64
#define NA 33600
#define NK 500
#define HW3 25600
#define HW4 6400
#define HW5 1600
#define OFF4 25600
#define OFF5 32000
#define NBIN 2048
#define CAP 2048
#define LCAP 1024

typedef unsigned int u32;
typedef unsigned long long u64;

__device__ __forceinline__ float sigf(float x) { return 1.0f / (1.0f + expf(-x)); }

__device__ __forceinline__ u32 f2key(float f) {
  u32 u = __float_as_uint(f);
  return (u & 0x80000000u) ? ~u : (u | 0x80000000u);
}
__device__ __forceinline__ float key2f(u32 k) {
  u32 u = (k & 0x80000000u) ? (k ^ 0x80000000u) : ~k;
  return __uint_as_float(u);
}
__device__ __forceinline__ int bin_of(float s) {
  int b = (int)(s * 2048.0f);
  return b > 2047 ? 2047 : b;   // monotone nondecreasing in s
}

// ---------------- K1: masked max-score -> key + per-batch histogram ----------
__global__ __launch_bounds__(256) void k_score(
    const float* __restrict__ cls3, const float* __restrict__ obj3,
    const float* __restrict__ cls4, const float* __restrict__ obj4,
    const float* __restrict__ cls5, const float* __restrict__ obj5,
    u32* __restrict__ keys, u32* __restrict__ ghist)
{
  int t = blockIdx.x * 256 + threadIdx.x;
  if (t >= NB * NA) return;
  int b = t / NA;
  int a = t - b * NA;
  const float* cls; const float* obj; int pos, HW;
  if (a < OFF4)      { cls = cls3; obj = obj3; pos = a;        HW = HW3; }
  else if (a < OFF5) { cls = cls4; obj = obj4; pos = a - OFF4; HW = HW4; }
  else               { cls = cls5; obj = obj5; pos = a - OFF5; HW = HW5; }
  float so = sigf(obj[b * HW + pos]);
  float s0 = so * sigf(cls[(b * 2) * HW + pos]);
  float s1 = so * sigf(cls[(b * 2 + 1) * HW + pos]);
  float s  = fmaxf(s0, s1);
  float masked = (s > 0.3f) ? s : -1.0f;
  keys[t] = f2key(masked);
  if (s > 0.3f) atomicAdd(&ghist[b * NBIN + bin_of(s)], 1u);
}

// ---------------- K2a: find pivot bin (max p with suffix(p) >= 500) ----------
__global__ __launch_bounds__(256) void k_pivot(
    const u32* __restrict__ ghist, int* __restrict__ pivot, int* __restrict__ ok)
{
  int b = blockIdx.x, t = threadIdx.x;
  __shared__ u32 hb[NBIN];
  __shared__ u32 part[256];
  const u32* h = ghist + b * NBIN;
  for (int i = t; i < NBIN; i += 256) hb[i] = h[i];
  __syncthreads();
  u32 s = 0;
#pragma unroll
  for (int k = 0; k < 8; ++k) s += hb[t * 8 + k];
  part[t] = s;
  __syncthreads();
  for (int off = 1; off < 256; off <<= 1) {
    u32 add = (t + off < 256) ? part[t + off] : 0u;
    __syncthreads();
    part[t] += add;
    __syncthreads();
  }
  u32 S = part[t];
  u32 Snext = (t == 255) ? 0u : part[t + 1];
  if (t == 0) { ok[b] = (part[0] >= NK) ? 1 : 0; if (part[0] < NK) pivot[b] = NBIN; }
  if (S >= NK && Snext < NK) {
    u32 run = Snext;
    int p = 0;
    for (int k = 7; k >= 0; --k) {
      run += hb[t * 8 + k];
      if (run >= NK) { p = t * 8 + k; break; }
    }
    pivot[b] = p;
  }
}

// ---------------- K2b: collect candidates (bin >= pivot), LDS-staged ---------
__global__ __launch_bounds__(256) void k_collect(
    const u32* __restrict__ keys, const int* __restrict__ pivot, int* __restrict__ ok,
    u64* __restrict__ cand, u32* __restrict__ cnt)
{
  int blk = blockIdx.x;
  int b = blk >> 2, seg = blk & 3;
  if (!ok[b]) return;
  int p = pivot[b];
  __shared__ u64 loc[LCAP];
  __shared__ u32 lcnt;
  __shared__ u32 gbase;
  if (threadIdx.x == 0) lcnt = 0;
  __syncthreads();

  const uint4* kb4 = reinterpret_cast<const uint4*>(keys + (size_t)b * NA);
  int base4 = seg * 2100;               // NA/4 = 8400 uint4, 4 segments
  for (int i4 = base4 + threadIdx.x; i4 < base4 + 2100; i4 += 256) {
    uint4 kv = kb4[i4];
    u32 ks[4] = {kv.x, kv.y, kv.z, kv.w};
#pragma unroll
    for (int c = 0; c < 4; ++c) {
      float s = key2f(ks[c]);
      if (s > 0.3f && bin_of(s) >= p) {
        u32 slot = atomicAdd(&lcnt, 1u);    // LDS atomic — cheap
        if (slot < LCAP)
          loc[slot] = ((u64)ks[c] << 16) | (u32)(0xFFFF - (i4 * 4 + c));
      }
    }
  }
  __syncthreads();
  if (threadIdx.x == 0) {
    u32 n = lcnt < LCAP ? lcnt : LCAP;
    gbase = atomicAdd(&cnt[b], n);          // ONE global atomic per block
    if (lcnt > LCAP) ok[b] = 0;             // lost candidates -> exact fallback
  }
  __syncthreads();
  u32 n = lcnt < LCAP ? lcnt : LCAP;
  u32 gb = gbase;
  for (u32 i = threadIdx.x; i < n; i += 256) {
    u32 slot = gb + i;
    if (slot < CAP) cand[(size_t)b * CAP + slot] = loc[i];
    // slot >= CAP => cnt[b] > CAP => k_rank flips ok[b], fallback handles it
  }
}

// ---------------- K2c: exact rank of candidates -> ordered top-500 -----------
__global__ __launch_bounds__(1024) void k_rank(
    const u64* __restrict__ cand, const u32* __restrict__ cnt, int* __restrict__ ok,
    int* __restrict__ top_idx, float* __restrict__ top_score)
{
  int b = blockIdx.x;
  if (!ok[b]) return;
  u32 n = cnt[b];
  if (n > CAP) { if (threadIdx.x == 0) ok[b] = 0; return; }
  __shared__ u64 coll[CAP];
  for (u32 i = threadIdx.x; i < n; i += 1024) coll[i] = cand[(size_t)b * CAP + i];
  __syncthreads();
  for (u32 t = threadIdx.x; t < n; t += 1024) {
    u64 k = coll[t];
    int rank = 0;
    for (u32 j = 0; j < n; ++j) rank += (coll[j] > k) ? 1 : 0;
    if (rank < NK) {
      top_idx[b * NK + rank]   = 0xFFFF - (int)(k & 0xFFFFull);
      top_score[b * NK + rank] = key2f((u32)(k >> 16));
    }
  }
}

// ---------------- K2-fallback: exact 48-bit radix select (rare path) ---------
__global__ __launch_bounds__(1024) void k_select_fb(
    const u32* __restrict__ keys, const int* __restrict__ ok,
    int* __restrict__ top_idx, float* __restrict__ top_score)
{
  int b = blockIdx.x;
  if (ok[b]) return;
  int tid = threadIdx.x;
  __shared__ u32 hist[256];
  __shared__ u32 suf[256];
  __shared__ u64 coll[512];
  __shared__ u32 sh_R;
  __shared__ int sh_digit;
  __shared__ u32 sh_cnt;
  const u32* kb = keys + (size_t)b * NA;
  if (tid == 0) sh_cnt = 0;

  u64 prefix = 0, prefmask = 0;
  u32 R = NK;
  for (int pass = 0; pass < 6; ++pass) {
    int shift = 40 - 8 * pass;
    if (tid < 256) hist[tid] = 0;
    __syncthreads();
    for (int i = tid; i < NA; i += 1024) {
      u64 k48 = ((u64)kb[i] << 16) | (u32)(0xFFFF - i);
      if ((k48 & prefmask) == prefix)
        atomicAdd(&hist[(u32)(k48 >> shift) & 255u], 1u);
    }
    __syncthreads();
    if (tid < 256) suf[tid] = hist[tid];
    __syncthreads();
    for (int off = 1; off < 256; off <<= 1) {
      u32 add = 0;
      if (tid < 256 && tid + off < 256) add = suf[tid + off];
      __syncthreads();
      if (tid < 256) suf[tid] += add;
      __syncthreads();
    }
    if (tid < 256) {
      u32 s = suf[tid];
      u32 snext = (tid == 255) ? 0u : suf[tid + 1];
      if (s >= R && snext < R) { sh_digit = tid; sh_R = R - snext; }
    }
    __syncthreads();
    int dsel = sh_digit;
    R = sh_R;
    prefix |= ((u64)dsel) << shift;
    prefmask |= 0xFFull << shift;
    __syncthreads();
  }

  for (int i = tid; i < NA; i += 1024) {
    u64 k48 = ((u64)kb[i] << 16) | (u32)(0xFFFF - i);
    if (k48 >= prefix) {
      u32 slot = atomicAdd(&sh_cnt, 1u);
      if (slot < 512) coll[slot] = k48;
    }
  }
  __syncthreads();
  int n = (sh_cnt < (u32)NK) ? (int)sh_cnt : NK;
  if (tid < NK) { top_idx[b * NK + tid] = 0; top_score[b * NK + tid] = -1.0f; }
  __syncthreads();
  for (int t = tid; t < n; t += 1024) {
    u64 k = coll[t];
    int rank = 0;
    for (int j = 0; j < n; ++j) rank += (coll[j] > k) ? 1 : 0;
    int idx = 0xFFFF - (int)(k & 0xFFFFull);
    top_idx[b * NK + rank] = idx;
    top_score[b * NK + rank] = key2f((u32)(k >> 16));
  }
}

// ---------------- K3: decode boxes + labels for selected anchors -------------
__global__ __launch_bounds__(256) void k_decode(
    const int* __restrict__ top_idx,
    const float* __restrict__ cls3, const float* __restrict__ obj3, const float* __restrict__ reg3,
    const float* __restrict__ cls4, const float* __restrict__ obj4, const float* __restrict__ reg4,
    const float* __restrict__ cls5, const float* __restrict__ obj5, const float* __restrict__ reg5,
    float4* __restrict__ boxes, float4* __restrict__ boxesoff,
    float* __restrict__ out_labels)
{
  int t = blockIdx.x * 256 + threadIdx.x;
  if (t >= NB * NK) return;
  int b = t / NK;
  int a = top_idx[t];
  const float *cls, *obj, *reg; int pos, HW, x, y; float stride;
  if (a < OFF4) {
    cls = cls3; obj = obj3; reg = reg3; pos = a; HW = HW3; stride = 8.0f;
    y = pos / 160; x = pos - y * 160;
  } else if (a < OFF5) {
    cls = cls4; obj = obj4; reg = reg4; pos = a - OFF4; HW = HW4; stride = 16.0f;
    y = pos / 80; x = pos - y * 80;
  } else {
    cls = cls5; obj = obj5; reg = reg5; pos = a - OFF5; HW = HW5; stride = 32.0f;
    y = pos / 40; x = pos - y * 40;
  }
  float dx = reg[(b * 4 + 0) * HW + pos];
  float dy = reg[(b * 4 + 1) * HW + pos];
  float dw = reg[(b * 4 + 2) * HW + pos];
  float dh = reg[(b * 4 + 3) * HW + pos];
  float cx = ((float)x + sigf(dx)) * stride;
  float cy = ((float)y + sigf(dy)) * stride;
  float w = expf(dw) * stride;
  float h = expf(dh) * stride;
  float x1 = cx - w * 0.5f, y1 = cy - h * 0.5f;
  float x2 = cx + w * 0.5f, y2 = cy + h * 0.5f;
  float so = sigf(obj[b * HW + pos]);
  float s0 = so * sigf(cls[(b * 2) * HW + pos]);
  float s1 = so * sigf(cls[(b * 2 + 1) * HW + pos]);
  int label = (s1 > s0) ? 1 : 0;
  float off = (float)label * 10000.0f;
  boxes[t]    = make_float4(x1, y1, x2, y2);
  boxesoff[t] = make_float4(x1 + off, y1 + off, x2 + off, y2 + off);
  out_labels[t] = (float)label;
}

// ---------------- K4: suppression bit-matrix (iou >= 0.5) --------------------
__global__ __launch_bounds__(256) void k_iou(
    const float4* __restrict__ boxesoff, u64* __restrict__ mask)
{
  int t = blockIdx.x * 256 + threadIdx.x;
  if (t >= NB * NK * 8) return;
  int w = t & 7;
  int bi = t >> 3;
  int b = bi / NK;
  float4 A = boxesoff[bi];
  float areaA = (A.z - A.x) * (A.w - A.y);
  const float4* base = boxesoff + b * NK;
  int j0 = w * 64;
  int jmax = (NK - j0 < 64) ? (NK - j0) : 64;
  u64 bits = 0;
  for (int jj = 0; jj < jmax; ++jj) {
    float4 Bx = base[j0 + jj];
    float areaB = (Bx.z - Bx.x) * (Bx.w - Bx.y);
    float ix1 = fmaxf(A.x, Bx.x);
    float iy1 = fmaxf(A.y, Bx.y);
    float ix2 = fminf(A.z, Bx.z);
    float iy2 = fminf(A.w, Bx.w);
    float iw = fmaxf(ix2 - ix1, 0.0f);
    float ih = fmaxf(iy2 - iy1, 0.0f);
    float inter = iw * ih;
    float uni = areaA + areaB - inter;
    float iou = inter / (uni + 1e-7f);
    bits |= ((u64)(iou >= 0.5f)) << jj;
  }
  mask[t] = bits;
}

// ---------------- K5: sequential greedy NMS scan + finalize ------------------
__global__ __launch_bounds__(64) void k_nms(
    const u64* __restrict__ mask, const float* __restrict__ top_score,
    const float4* __restrict__ boxes,
    float* __restrict__ out_boxes, float* __restrict__ out_scores,
    float* __restrict__ out_keep)
{
  __shared__ __align__(16) u64 m[504 * 8];
  int b = blockIdx.x;
  int lane = threadIdx.x;
  const u64* mb = mask + (size_t)b * (NK * 8);
  for (int i = lane; i < NK * 8; i += 64) m[i] = mb[i];
  if (lane < 32) m[NK * 8 + lane] = 0;

  u64 validw[8];
#pragma unroll
  for (int c = 0; c < 8; ++c) {
    int r = c * 64 + lane;
    float s = (r < NK) ? top_score[b * NK + r] : -1.0f;
    validw[c] = __ballot(s > 0.3f);
  }
  __syncthreads();

  const ulonglong2* m2 = reinterpret_cast<const ulonglong2*>(m);
  u64 supp[8] = {0, 0, 0, 0, 0, 0, 0, 0};
  u64 kw[8]   = {0, 0, 0, 0, 0, 0, 0, 0};

#pragma unroll
  for (int w = 0; w < 8; ++w) {
    const int WP2 = (w & ~1) >> 1;
    const int IMAX = (w == 7) ? 52 : 64;
    ulonglong2 A[4], Bv[4];
#pragma unroll
    for (int p = 0; p < 4; ++p) A[p] = m2[(w * 64 + 0) * 4 + p];
#pragma unroll
    for (int p = 0; p < 4; ++p) Bv[p] = m2[(w * 64 + 1) * 4 + p];
    u64 vw = validw[w];
    for (int ib = 0; ib < IMAX; ib += 2) {
      int i = w * 64 + ib;
      {
        ulonglong2 S[4];
#pragma unroll
        for (int p = 0; p < 4; ++p) S[p] = A[p];
#pragma unroll
        for (int p = 0; p < 4; ++p) if (p >= WP2) A[p] = m2[(i + 2) * 4 + p];
        bool kp = (((vw >> ib) & 1ull) != 0) && (((supp[w] >> ib) & 1ull) == 0);
        if (kp) {
          kw[w] |= (1ull << ib);
#pragma unroll
          for (int p = 0; p < 4; ++p) if (p >= WP2) {
            supp[2 * p]     |= S[p].x;
            supp[2 * p + 1] |= S[p].y;
          }
        }
      }
      {
        int ib1 = ib + 1;
        ulonglong2 S[4];
#pragma unroll
        for (int p = 0; p < 4; ++p) S[p] = Bv[p];
#pragma unroll
        for (int p = 0; p < 4; ++p) if (p >= WP2) Bv[p] = m2[(i + 3) * 4 + p];
        bool kp = (((vw >> ib1) & 1ull) != 0) && (((supp[w] >> ib1) & 1ull) == 0);
        if (kp) {
          kw[w] |= (1ull << ib1);
#pragma unroll
          for (int p = 0; p < 4; ++p) if (p >= WP2) {
            supp[2 * p]     |= S[p].x;
            supp[2 * p + 1] |= S[p].y;
          }
        }
      }
    }
  }

#pragma unroll
  for (int c = 0; c < 8; ++c) {
    int r = c * 64 + lane;
    if (r < NK) {
      int kp = (int)((kw[c] >> lane) & 1ull);
      float4 bx = boxes[b * NK + r];
      float s = top_score[b * NK + r];
      float4 ob;
      ob.x = kp ? bx.x : 0.0f;
      ob.y = kp ? bx.y : 0.0f;
      ob.z = kp ? bx.z : 0.0f;
      ob.w = kp ? bx.w : 0.0f;
      reinterpret_cast<float4*>(out_boxes)[b * NK + r] = ob;
      out_scores[b * NK + r] = kp ? s : 0.0f;
      out_keep[b * NK + r]   = kp ? 1.0f : 0.0f;
    }
  }
}

// ---------------- launcher ---------------------------------------------------
extern "C" void kernel_launch(void* const* d_in, const int* in_sizes, int n_in,
                              void* d_out, int out_size, void* d_ws, size_t ws_size,
                              hipStream_t stream) {
  const float* cls3 = (const float*)d_in[0];
  const float* reg3 = (const float*)d_in[1];
  const float* obj3 = (const float*)d_in[2];
  const float* cls4 = (const float*)d_in[3];
  const float* reg4 = (const float*)d_in[4];
  const float* obj4 = (const float*)d_in[5];
  const float* cls5 = (const float*)d_in[6];
  const float* reg5 = (const float*)d_in[7];
  const float* obj5 = (const float*)d_in[8];

  char* ws = (char*)d_ws;
  u32*    keys      = (u32*)   (ws + 0);          //  8,601,600
  u32*    ghist     = (u32*)   (ws + 8601600);    //    524,288
  u32*    cnt       = (u32*)   (ws + 9125888);    //        256
  int*    pivot     = (int*)   (ws + 9126144);    //        256
  int*    ok        = (int*)   (ws + 9126400);    //        256
  u64*    cand      = (u64*)   (ws + 9126656);    //  1,048,576
  int*    top_idx   = (int*)   (ws + 10175232);   //    128,000
  float*  top_score = (float*) (ws + 10303232);   //    128,000
  float4* boxes     = (float4*)(ws + 10431232);   //    512,000
  float4* boxesoff  = (float4*)(ws + 10943232);   //    512,000
  u64*    mask      = (u64*)   (ws + 11455232);   //  2,048,000  (end ~13.5 MB)

  float* out        = (float*)d_out;
  float* out_boxes  = out;
  float* out_scores = out + 128000;
  float* out_labels = out + 160000;
  float* out_keep   = out + 192000;

  hipMemsetAsync(ghist, 0, 524288 + 256, stream);  // ghist + cnt
  k_score<<<(NB * NA + 255) / 256, 256, 0, stream>>>(cls3, obj3, cls4, obj4, cls5, obj5, keys, ghist);
  k_pivot<<<NB, 256, 0, stream>>>(ghist, pivot, ok);
  k_collect<<<NB * 4, 256, 0, stream>>>(keys, pivot, ok, cand, cnt);
  k_rank<<<NB, 1024, 0, stream>>>(cand, cnt, ok, top_idx, top_score);
  k_select_fb<<<NB, 1024, 0, stream>>>(keys, ok, top_idx, top_score);
  k_decode<<<(NB * NK + 255) / 256, 256, 0, stream>>>(top_idx,
      cls3, obj3, reg3, cls4, obj4, reg4, cls5, obj5, reg5,
      boxes, boxesoff, out_labels);
  k_iou<<<(NB * NK * 8 + 255) / 256, 256, 0, stream>>>(boxesoff, mask);
  k_nms<<<NB, 64, 0, stream>>>(mask, top_score, boxes, out_boxes, out_scores, out_keep);
}

// Round 4
// 132.097 us; speedup vs baseline: 2.3029x; 1.6208x over previous
//
#include <hip/hip_runtime.h>
#include <hip/hip_bf16.h>
#include <stdint.h>

#define NB 64
#define NA 33600
#define NK 500
#define HW3 25600
#define HW4 6400
#define HW5 1600
#define OFF4 25600
#define OFF5 32000
#define NBIN 2048
#define CAP 2048
#define NA4 8400

typedef unsigned int u32;
typedef unsigned long long u64;

__device__ __forceinline__ float sigf(float x) { return 1.0f / (1.0f + expf(-x)); }

__device__ __forceinline__ u32 f2key(float f) {
  u32 u = __float_as_uint(f);
  return (u & 0x80000000u) ? ~u : (u | 0x80000000u);
}
__device__ __forceinline__ float key2f(u32 k) {
  u32 u = (k & 0x80000000u) ? (k ^ 0x80000000u) : ~k;
  return __uint_as_float(u);
}
__device__ __forceinline__ int bin_of(float s) {
  int b = (int)(s * 2048.0f);
  return b > 2047 ? 2047 : b;   // monotone nondecreasing in s
}
__device__ __forceinline__ u32 mkkey(float o, float c0, float c1) {
  float so = sigf(o);
  float s = fmaxf(so * sigf(c0), so * sigf(c1));
  float masked = (s > 0.3f) ? s : -1.0f;
  return f2key(masked);
}

// ---------------- K1: masked max-score -> keys (pure streaming, float4) ------
__global__ __launch_bounds__(256) void k_score(
    const float* __restrict__ cls3, const float* __restrict__ obj3,
    const float* __restrict__ cls4, const float* __restrict__ obj4,
    const float* __restrict__ cls5, const float* __restrict__ obj5,
    uint4* __restrict__ keys4)
{
  int b = blockIdx.y;
  int i4 = blockIdx.x * 256 + threadIdx.x;       // float4-granular anchor index
  if (i4 >= NA4) return;
  const float* cls; const float* obj; int p4, HW;
  if (i4 < 6400)      { cls = cls3; obj = obj3; p4 = i4;        HW = HW3; }
  else if (i4 < 8000) { cls = cls4; obj = obj4; p4 = i4 - 6400; HW = HW4; }
  else                { cls = cls5; obj = obj5; p4 = i4 - 8000; HW = HW5; }
  float4 o  = reinterpret_cast<const float4*>(obj + (size_t)b * HW)[p4];
  float4 c0 = reinterpret_cast<const float4*>(cls + (size_t)(b * 2) * HW)[p4];
  float4 c1 = reinterpret_cast<const float4*>(cls + (size_t)(b * 2 + 1) * HW)[p4];
  uint4 kv;
  kv.x = mkkey(o.x, c0.x, c1.x);
  kv.y = mkkey(o.y, c0.y, c1.y);
  kv.z = mkkey(o.z, c0.z, c1.z);
  kv.w = mkkey(o.w, c0.w, c1.w);
  keys4[(size_t)b * NA4 + i4] = kv;
}

// ---------------- K2: fused hist+pivot+collect+rank (all LDS, 1 block/batch) -
__global__ __launch_bounds__(1024) void k_topk(
    const u32* __restrict__ keys, int* __restrict__ ok,
    int* __restrict__ top_idx, float* __restrict__ top_score)
{
  int b = blockIdx.x, tid = threadIdx.x;
  __shared__ u32 hist[NBIN];
  __shared__ u32 part[256];
  __shared__ u64 cand[CAP];
  __shared__ u32 lcnt;
  __shared__ int sh_p;
  for (int i = tid; i < NBIN; i += 1024) hist[i] = 0;
  if (tid == 0) lcnt = 0;
  __syncthreads();

  const uint4* kb4 = reinterpret_cast<const uint4*>(keys + (size_t)b * NA);
  // pass 1: LDS histogram of scores > 0.3
  for (int i4 = tid; i4 < NA4; i4 += 1024) {
    uint4 kv = kb4[i4];
    u32 ks[4] = {kv.x, kv.y, kv.z, kv.w};
#pragma unroll
    for (int c = 0; c < 4; ++c) {
      float s = key2f(ks[c]);
      if (s > 0.3f) atomicAdd(&hist[bin_of(s)], 1u);
    }
  }
  __syncthreads();
  // suffix scan over 256 groups of 8 bins
  if (tid < 256) {
    u32 s8 = 0;
#pragma unroll
    for (int k = 0; k < 8; ++k) s8 += hist[tid * 8 + k];
    part[tid] = s8;
  }
  __syncthreads();
  for (int off = 1; off < 256; off <<= 1) {
    u32 add = 0;
    if (tid < 256 && tid + off < 256) add = part[tid + off];
    __syncthreads();
    if (tid < 256) part[tid] += add;
    __syncthreads();
  }
  if (tid == 0 && part[0] < NK) sh_p = -1;            // fewer than 500 valid
  if (tid < 256) {
    u32 S = part[tid];
    u32 Snext = (tid == 255) ? 0u : part[tid + 1];
    if (S >= NK && Snext < NK) {
      u32 run = Snext;
      int p = tid * 8;
      for (int k = 7; k >= 0; --k) {
        run += hist[tid * 8 + k];
        if (run >= NK) { p = tid * 8 + k; break; }
      }
      sh_p = p;
    }
  }
  __syncthreads();
  int p = sh_p;
  if (p < 0) { if (tid == 0) ok[b] = 0; return; }     // radix fallback
  // pass 2: collect candidates with bin >= pivot into LDS
  for (int i4 = tid; i4 < NA4; i4 += 1024) {
    uint4 kv = kb4[i4];
    u32 ks[4] = {kv.x, kv.y, kv.z, kv.w};
#pragma unroll
    for (int c = 0; c < 4; ++c) {
      float s = key2f(ks[c]);
      if (s > 0.3f && bin_of(s) >= p) {
        u32 slot = atomicAdd(&lcnt, 1u);
        if (slot < CAP) cand[slot] = ((u64)ks[c] << 16) | (u32)(0xFFFF - (i4 * 4 + c));
      }
    }
  }
  __syncthreads();
  if (lcnt > CAP) { if (tid == 0) ok[b] = 0; return; }  // overflow -> fallback
  if (tid == 0) ok[b] = 1;
  int n = (int)lcnt;
  // counting-rank (keys distinct -> unique ranks), write ordered top-500
  for (int t = tid; t < n; t += 1024) {
    u64 k = cand[t];
    int rank = 0;
    for (int j = 0; j < n; ++j) rank += (cand[j] > k) ? 1 : 0;
    if (rank < NK) {
      top_idx[b * NK + rank]   = 0xFFFF - (int)(k & 0xFFFFull);
      top_score[b * NK + rank] = key2f((u32)(k >> 16));
    }
  }
}

// ---------------- K2-fallback: exact 48-bit radix select (rare path) ---------
__global__ __launch_bounds__(1024) void k_select_fb(
    const u32* __restrict__ keys, const int* __restrict__ ok,
    int* __restrict__ top_idx, float* __restrict__ top_score)
{
  int b = blockIdx.x;
  if (ok[b]) return;
  int tid = threadIdx.x;
  __shared__ u32 hist[256];
  __shared__ u32 suf[256];
  __shared__ u64 coll[512];
  __shared__ u32 sh_R;
  __shared__ int sh_digit;
  __shared__ u32 sh_cnt;
  const u32* kb = keys + (size_t)b * NA;
  if (tid == 0) sh_cnt = 0;

  u64 prefix = 0, prefmask = 0;
  u32 R = NK;
  for (int pass = 0; pass < 6; ++pass) {
    int shift = 40 - 8 * pass;
    if (tid < 256) hist[tid] = 0;
    __syncthreads();
    for (int i = tid; i < NA; i += 1024) {
      u64 k48 = ((u64)kb[i] << 16) | (u32)(0xFFFF - i);
      if ((k48 & prefmask) == prefix)
        atomicAdd(&hist[(u32)(k48 >> shift) & 255u], 1u);
    }
    __syncthreads();
    if (tid < 256) suf[tid] = hist[tid];
    __syncthreads();
    for (int off = 1; off < 256; off <<= 1) {
      u32 add = 0;
      if (tid < 256 && tid + off < 256) add = suf[tid + off];
      __syncthreads();
      if (tid < 256) suf[tid] += add;
      __syncthreads();
    }
    if (tid < 256) {
      u32 s = suf[tid];
      u32 snext = (tid == 255) ? 0u : suf[tid + 1];
      if (s >= R && snext < R) { sh_digit = tid; sh_R = R - snext; }
    }
    __syncthreads();
    int dsel = sh_digit;
    R = sh_R;
    prefix |= ((u64)dsel) << shift;
    prefmask |= 0xFFull << shift;
    __syncthreads();
  }

  for (int i = tid; i < NA; i += 1024) {
    u64 k48 = ((u64)kb[i] << 16) | (u32)(0xFFFF - i);
    if (k48 >= prefix) {
      u32 slot = atomicAdd(&sh_cnt, 1u);
      if (slot < 512) coll[slot] = k48;
    }
  }
  __syncthreads();
  int n = (sh_cnt < (u32)NK) ? (int)sh_cnt : NK;
  if (tid < NK) { top_idx[b * NK + tid] = 0; top_score[b * NK + tid] = -1.0f; }
  __syncthreads();
  for (int t = tid; t < n; t += 1024) {
    u64 k = coll[t];
    int rank = 0;
    for (int j = 0; j < n; ++j) rank += (coll[j] > k) ? 1 : 0;
    int idx = 0xFFFF - (int)(k & 0xFFFFull);
    top_idx[b * NK + rank] = idx;
    top_score[b * NK + rank] = key2f((u32)(k >> 16));
  }
}

// ---------------- K3: decode boxes + labels for selected anchors -------------
__global__ __launch_bounds__(256) void k_decode(
    const int* __restrict__ top_idx,
    const float* __restrict__ cls3, const float* __restrict__ obj3, const float* __restrict__ reg3,
    const float* __restrict__ cls4, const float* __restrict__ obj4, const float* __restrict__ reg4,
    const float* __restrict__ cls5, const float* __restrict__ obj5, const float* __restrict__ reg5,
    float4* __restrict__ boxes, float4* __restrict__ boxesoff,
    float* __restrict__ out_labels)
{
  int t = blockIdx.x * 256 + threadIdx.x;
  if (t >= NB * NK) return;
  int b = t / NK;
  int a = top_idx[t];
  const float *cls, *obj, *reg; int pos, HW, x, y; float stride;
  if (a < OFF4) {
    cls = cls3; obj = obj3; reg = reg3; pos = a; HW = HW3; stride = 8.0f;
    y = pos / 160; x = pos - y * 160;
  } else if (a < OFF5) {
    cls = cls4; obj = obj4; reg = reg4; pos = a - OFF4; HW = HW4; stride = 16.0f;
    y = pos / 80; x = pos - y * 80;
  } else {
    cls = cls5; obj = obj5; reg = reg5; pos = a - OFF5; HW = HW5; stride = 32.0f;
    y = pos / 40; x = pos - y * 40;
  }
  float dx = reg[(b * 4 + 0) * HW + pos];
  float dy = reg[(b * 4 + 1) * HW + pos];
  float dw = reg[(b * 4 + 2) * HW + pos];
  float dh = reg[(b * 4 + 3) * HW + pos];
  float cx = ((float)x + sigf(dx)) * stride;
  float cy = ((float)y + sigf(dy)) * stride;
  float w = expf(dw) * stride;
  float h = expf(dh) * stride;
  float x1 = cx - w * 0.5f, y1 = cy - h * 0.5f;
  float x2 = cx + w * 0.5f, y2 = cy + h * 0.5f;
  float so = sigf(obj[b * HW + pos]);
  float s0 = so * sigf(cls[(b * 2) * HW + pos]);
  float s1 = so * sigf(cls[(b * 2 + 1) * HW + pos]);
  int label = (s1 > s0) ? 1 : 0;
  float off = (float)label * 10000.0f;
  boxes[t]    = make_float4(x1, y1, x2, y2);
  boxesoff[t] = make_float4(x1 + off, y1 + off, x2 + off, y2 + off);
  out_labels[t] = (float)label;
}

// ---------------- K4: suppression bit-matrix (iou >= 0.5) --------------------
__global__ __launch_bounds__(256) void k_iou(
    const float4* __restrict__ boxesoff, u64* __restrict__ mask)
{
  int t = blockIdx.x * 256 + threadIdx.x;
  if (t >= NB * NK * 8) return;
  int w = t & 7;
  int bi = t >> 3;
  int b = bi / NK;
  float4 A = boxesoff[bi];
  float areaA = (A.z - A.x) * (A.w - A.y);
  const float4* base = boxesoff + b * NK;
  int j0 = w * 64;
  int jmax = (NK - j0 < 64) ? (NK - j0) : 64;
  u64 bits = 0;
  for (int jj = 0; jj < jmax; ++jj) {
    float4 Bx = base[j0 + jj];
    float areaB = (Bx.z - Bx.x) * (Bx.w - Bx.y);
    float ix1 = fmaxf(A.x, Bx.x);
    float iy1 = fmaxf(A.y, Bx.y);
    float ix2 = fminf(A.z, Bx.z);
    float iy2 = fminf(A.w, Bx.w);
    float iw = fmaxf(ix2 - ix1, 0.0f);
    float ih = fmaxf(iy2 - iy1, 0.0f);
    float inter = iw * ih;
    float uni = areaA + areaB - inter;
    float iou = inter / (uni + 1e-7f);
    bits |= ((u64)(iou >= 0.5f)) << jj;
  }
  mask[t] = bits;
}

// ---------------- K5: sequential greedy NMS scan + finalize ------------------
__global__ __launch_bounds__(64) void k_nms(
    const u64* __restrict__ mask, const float* __restrict__ top_score,
    const float4* __restrict__ boxes,
    float* __restrict__ out_boxes, float* __restrict__ out_scores,
    float* __restrict__ out_keep)
{
  __shared__ __align__(16) u64 m[504 * 8];
  int b = blockIdx.x;
  int lane = threadIdx.x;
  const u64* mb = mask + (size_t)b * (NK * 8);
  for (int i = lane; i < NK * 8; i += 64) m[i] = mb[i];
  if (lane < 32) m[NK * 8 + lane] = 0;

  u64 validw[8];
#pragma unroll
  for (int c = 0; c < 8; ++c) {
    int r = c * 64 + lane;
    float s = (r < NK) ? top_score[b * NK + r] : -1.0f;
    validw[c] = __ballot(s > 0.3f);
  }
  __syncthreads();

  const ulonglong2* m2 = reinterpret_cast<const ulonglong2*>(m);
  u64 supp[8] = {0, 0, 0, 0, 0, 0, 0, 0};
  u64 kw[8]   = {0, 0, 0, 0, 0, 0, 0, 0};

#pragma unroll
  for (int w = 0; w < 8; ++w) {
    const int WP2 = (w & ~1) >> 1;
    const int IMAX = (w == 7) ? 52 : 64;
    ulonglong2 A[4], Bv[4];
#pragma unroll
    for (int p = 0; p < 4; ++p) A[p] = m2[(w * 64 + 0) * 4 + p];
#pragma unroll
    for (int p = 0; p < 4; ++p) Bv[p] = m2[(w * 64 + 1) * 4 + p];
    u64 vw = validw[w];
    for (int ib = 0; ib < IMAX; ib += 2) {
      int i = w * 64 + ib;
      {
        ulonglong2 S[4];
#pragma unroll
        for (int p = 0; p < 4; ++p) S[p] = A[p];
#pragma unroll
        for (int p = 0; p < 4; ++p) if (p >= WP2) A[p] = m2[(i + 2) * 4 + p];
        bool kp = (((vw >> ib) & 1ull) != 0) && (((supp[w] >> ib) & 1ull) == 0);
        if (kp) {
          kw[w] |= (1ull << ib);
#pragma unroll
          for (int p = 0; p < 4; ++p) if (p >= WP2) {
            supp[2 * p]     |= S[p].x;
            supp[2 * p + 1] |= S[p].y;
          }
        }
      }
      {
        int ib1 = ib + 1;
        ulonglong2 S[4];
#pragma unroll
        for (int p = 0; p < 4; ++p) S[p] = Bv[p];
#pragma unroll
        for (int p = 0; p < 4; ++p) if (p >= WP2) Bv[p] = m2[(i + 3) * 4 + p];
        bool kp = (((vw >> ib1) & 1ull) != 0) && (((supp[w] >> ib1) & 1ull) == 0);
        if (kp) {
          kw[w] |= (1ull << ib1);
#pragma unroll
          for (int p = 0; p < 4; ++p) if (p >= WP2) {
            supp[2 * p]     |= S[p].x;
            supp[2 * p + 1] |= S[p].y;
          }
        }
      }
    }
  }

#pragma unroll
  for (int c = 0; c < 8; ++c) {
    int r = c * 64 + lane;
    if (r < NK) {
      int kp = (int)((kw[c] >> lane) & 1ull);
      float4 bx = boxes[b * NK + r];
      float s = top_score[b * NK + r];
      float4 ob;
      ob.x = kp ? bx.x : 0.0f;
      ob.y = kp ? bx.y : 0.0f;
      ob.z = kp ? bx.z : 0.0f;
      ob.w = kp ? bx.w : 0.0f;
      reinterpret_cast<float4*>(out_boxes)[b * NK + r] = ob;
      out_scores[b * NK + r] = kp ? s : 0.0f;
      out_keep[b * NK + r]   = kp ? 1.0f : 0.0f;
    }
  }
}

// ---------------- launcher ---------------------------------------------------
extern "C" void kernel_launch(void* const* d_in, const int* in_sizes, int n_in,
                              void* d_out, int out_size, void* d_ws, size_t ws_size,
                              hipStream_t stream) {
  const float* cls3 = (const float*)d_in[0];
  const float* reg3 = (const float*)d_in[1];
  const float* obj3 = (const float*)d_in[2];
  const float* cls4 = (const float*)d_in[3];
  const float* reg4 = (const float*)d_in[4];
  const float* obj4 = (const float*)d_in[5];
  const float* cls5 = (const float*)d_in[6];
  const float* reg5 = (const float*)d_in[7];
  const float* obj5 = (const float*)d_in[8];

  char* ws = (char*)d_ws;
  u32*    keys      = (u32*)   (ws + 0);          //  8,601,600
  int*    ok        = (int*)   (ws + 8601600);    //        256
  int*    top_idx   = (int*)   (ws + 8601856);    //    128,000
  float*  top_score = (float*) (ws + 8729856);    //    128,000
  float4* boxes     = (float4*)(ws + 8857856);    //    512,000
  float4* boxesoff  = (float4*)(ws + 9369856);    //    512,000
  u64*    mask      = (u64*)   (ws + 9881856);    //  2,048,000  (end ~11.9 MB)

  float* out        = (float*)d_out;
  float* out_boxes  = out;
  float* out_scores = out + 128000;
  float* out_labels = out + 160000;
  float* out_keep   = out + 192000;

  dim3 gscore((NA4 + 255) / 256, NB);
  k_score<<<gscore, 256, 0, stream>>>(cls3, obj3, cls4, obj4, cls5, obj5, (uint4*)keys);
  k_topk<<<NB, 1024, 0, stream>>>(keys, ok, top_idx, top_score);
  k_select_fb<<<NB, 1024, 0, stream>>>(keys, ok, top_idx, top_score);
  k_decode<<<(NB * NK + 255) / 256, 256, 0, stream>>>(top_idx,
      cls3, obj3, reg3, cls4, obj4, reg4, cls5, obj5, reg5,
      boxes, boxesoff, out_labels);
  k_iou<<<(NB * NK * 8 + 255) / 256, 256, 0, stream>>>(boxesoff, mask);
  k_nms<<<NB, 64, 0, stream>>>(mask, top_score, boxes, out_boxes, out_scores, out_keep);
}

// Round 6
// 106.899 us; speedup vs baseline: 2.8457x; 1.2357x over previous
//
#include <hip/hip_runtime.h>
#include <hip/hip_bf16.h>
#include <stdint.h>

#define NB 64
#define NA 33600
#define NK 500
#define HW3 25600
#define HW4 6400
#define HW5 1600
#define OFF4 25600
#define OFF5 32000
#define NBIN 2048
#define CAP 2048
#define NA4 8400
#define MROWS 512   // padded rows per batch in mask (512*8 u64 = 32 KB/batch)

typedef unsigned int u32;
typedef unsigned long long u64;

__device__ __forceinline__ float sigf(float x) { return 1.0f / (1.0f + expf(-x)); }

__device__ __forceinline__ u32 f2key(float f) {
  u32 u = __float_as_uint(f);
  return (u & 0x80000000u) ? ~u : (u | 0x80000000u);
}
__device__ __forceinline__ float key2f(u32 k) {
  u32 u = (k & 0x80000000u) ? (k ^ 0x80000000u) : ~k;
  return __uint_as_float(u);
}
__device__ __forceinline__ int bin_of(float s) {
  int b = (int)(s * 2048.0f);
  return b > 2047 ? 2047 : b;   // monotone nondecreasing in s
}
__device__ __forceinline__ u32 mkkey(float o, float c0, float c1) {
  float so = sigf(o);
  float s = fmaxf(so * sigf(c0), so * sigf(c1));
  float masked = (s > 0.3f) ? s : -1.0f;
  return f2key(masked);
}

// ---------------- K1: masked max-score -> keys (pure streaming, float4) ------
__global__ __launch_bounds__(256) void k_score(
    const float* __restrict__ cls3, const float* __restrict__ obj3,
    const float* __restrict__ cls4, const float* __restrict__ obj4,
    const float* __restrict__ cls5, const float* __restrict__ obj5,
    uint4* __restrict__ keys4)
{
  int b = blockIdx.y;
  int i4 = blockIdx.x * 256 + threadIdx.x;       // float4-granular anchor index
  if (i4 >= NA4) return;
  const float* cls; const float* obj; int p4, HW;
  if (i4 < 6400)      { cls = cls3; obj = obj3; p4 = i4;        HW = HW3; }
  else if (i4 < 8000) { cls = cls4; obj = obj4; p4 = i4 - 6400; HW = HW4; }
  else                { cls = cls5; obj = obj5; p4 = i4 - 8000; HW = HW5; }
  float4 o  = reinterpret_cast<const float4*>(obj + (size_t)b * HW)[p4];
  float4 c0 = reinterpret_cast<const float4*>(cls + (size_t)(b * 2) * HW)[p4];
  float4 c1 = reinterpret_cast<const float4*>(cls + (size_t)(b * 2 + 1) * HW)[p4];
  uint4 kv;
  kv.x = mkkey(o.x, c0.x, c1.x);
  kv.y = mkkey(o.y, c0.y, c1.y);
  kv.z = mkkey(o.z, c0.z, c1.z);
  kv.w = mkkey(o.w, c0.w, c1.w);
  keys4[(size_t)b * NA4 + i4] = kv;
}

// ---------------- K2: fused hist+pivot+collect+rank (all LDS, 1 block/batch) -
__global__ __launch_bounds__(1024) void k_topk(
    const u32* __restrict__ keys, int* __restrict__ ok,
    int* __restrict__ top_idx, float* __restrict__ top_score)
{
  int b = blockIdx.x, tid = threadIdx.x;
  __shared__ u32 hist[NBIN];
  __shared__ u32 part[256];
  __shared__ u64 cand[CAP];
  __shared__ u32 lcnt;
  __shared__ int sh_p;
  for (int i = tid; i < NBIN; i += 1024) hist[i] = 0;
  if (tid == 0) lcnt = 0;
  __syncthreads();

  const uint4* kb4 = reinterpret_cast<const uint4*>(keys + (size_t)b * NA);
  // pass 1: LDS histogram of scores > 0.3
  for (int i4 = tid; i4 < NA4; i4 += 1024) {
    uint4 kv = kb4[i4];
    u32 ks[4] = {kv.x, kv.y, kv.z, kv.w};
#pragma unroll
    for (int c = 0; c < 4; ++c) {
      float s = key2f(ks[c]);
      if (s > 0.3f) atomicAdd(&hist[bin_of(s)], 1u);
    }
  }
  __syncthreads();
  // suffix scan over 256 groups of 8 bins
  if (tid < 256) {
    u32 s8 = 0;
#pragma unroll
    for (int k = 0; k < 8; ++k) s8 += hist[tid * 8 + k];
    part[tid] = s8;
  }
  __syncthreads();
  for (int off = 1; off < 256; off <<= 1) {
    u32 add = 0;
    if (tid < 256 && tid + off < 256) add = part[tid + off];
    __syncthreads();
    if (tid < 256) part[tid] += add;
    __syncthreads();
  }
  if (tid == 0 && part[0] < NK) sh_p = -1;            // fewer than 500 valid
  if (tid < 256) {
    u32 S = part[tid];
    u32 Snext = (tid == 255) ? 0u : part[tid + 1];
    if (S >= NK && Snext < NK) {
      u32 run = Snext;
      int p = tid * 8;
      for (int k = 7; k >= 0; --k) {
        run += hist[tid * 8 + k];
        if (run >= NK) { p = tid * 8 + k; break; }
      }
      sh_p = p;
    }
  }
  __syncthreads();
  int p = sh_p;
  if (p < 0) { if (tid == 0) ok[b] = 0; return; }     // radix fallback
  // pass 2: collect candidates with bin >= pivot into LDS
  for (int i4 = tid; i4 < NA4; i4 += 1024) {
    uint4 kv = kb4[i4];
    u32 ks[4] = {kv.x, kv.y, kv.z, kv.w};
#pragma unroll
    for (int c = 0; c < 4; ++c) {
      float s = key2f(ks[c]);
      if (s > 0.3f && bin_of(s) >= p) {
        u32 slot = atomicAdd(&lcnt, 1u);
        if (slot < CAP) cand[slot] = ((u64)ks[c] << 16) | (u32)(0xFFFF - (i4 * 4 + c));
      }
    }
  }
  __syncthreads();
  if (lcnt > CAP) { if (tid == 0) ok[b] = 0; return; }  // overflow -> fallback
  if (tid == 0) ok[b] = 1;
  int n = (int)lcnt;
  // counting-rank (keys distinct -> unique ranks), write ordered top-500
  for (int t = tid; t < n; t += 1024) {
    u64 k = cand[t];
    int rank = 0;
    for (int j = 0; j < n; ++j) rank += (cand[j] > k) ? 1 : 0;
    if (rank < NK) {
      top_idx[b * NK + rank]   = 0xFFFF - (int)(k & 0xFFFFull);
      top_score[b * NK + rank] = key2f((u32)(k >> 16));
    }
  }
}

// ---------------- K2-fallback: exact 48-bit radix select (rare path) ---------
__global__ __launch_bounds__(1024) void k_select_fb(
    const u32* __restrict__ keys, const int* __restrict__ ok,
    int* __restrict__ top_idx, float* __restrict__ top_score)
{
  int b = blockIdx.x;
  if (ok[b]) return;
  int tid = threadIdx.x;
  __shared__ u32 hist[256];
  __shared__ u32 suf[256];
  __shared__ u64 coll[512];
  __shared__ u32 sh_R;
  __shared__ int sh_digit;
  __shared__ u32 sh_cnt;
  const u32* kb = keys + (size_t)b * NA;
  if (tid == 0) sh_cnt = 0;

  u64 prefix = 0, prefmask = 0;
  u32 R = NK;
  for (int pass = 0; pass < 6; ++pass) {
    int shift = 40 - 8 * pass;
    if (tid < 256) hist[tid] = 0;
    __syncthreads();
    for (int i = tid; i < NA; i += 1024) {
      u64 k48 = ((u64)kb[i] << 16) | (u32)(0xFFFF - i);
      if ((k48 & prefmask) == prefix)
        atomicAdd(&hist[(u32)(k48 >> shift) & 255u], 1u);
    }
    __syncthreads();
    if (tid < 256) suf[tid] = hist[tid];
    __syncthreads();
    for (int off = 1; off < 256; off <<= 1) {
      u32 add = 0;
      if (tid < 256 && tid + off < 256) add = suf[tid + off];
      __syncthreads();
      if (tid < 256) suf[tid] += add;
      __syncthreads();
    }
    if (tid < 256) {
      u32 s = suf[tid];
      u32 snext = (tid == 255) ? 0u : suf[tid + 1];
      if (s >= R && snext < R) { sh_digit = tid; sh_R = R - snext; }
    }
    __syncthreads();
    int dsel = sh_digit;
    R = sh_R;
    prefix |= ((u64)dsel) << shift;
    prefmask |= 0xFFull << shift;
    __syncthreads();
  }

  for (int i = tid; i < NA; i += 1024) {
    u64 k48 = ((u64)kb[i] << 16) | (u32)(0xFFFF - i);
    if (k48 >= prefix) {
      u32 slot = atomicAdd(&sh_cnt, 1u);
      if (slot < 512) coll[slot] = k48;
    }
  }
  __syncthreads();
  int n = (sh_cnt < (u32)NK) ? (int)sh_cnt : NK;
  if (tid < NK) { top_idx[b * NK + tid] = 0; top_score[b * NK + tid] = -1.0f; }
  __syncthreads();
  for (int t = tid; t < n; t += 1024) {
    u64 k = coll[t];
    int rank = 0;
    for (int j = 0; j < n; ++j) rank += (coll[j] > k) ? 1 : 0;
    int idx = 0xFFFF - (int)(k & 0xFFFFull);
    top_idx[b * NK + rank] = idx;
    top_score[b * NK + rank] = key2f((u32)(k >> 16));
  }
}

// ---------------- K3: decode boxes + labels for selected anchors -------------
__global__ __launch_bounds__(256) void k_decode(
    const int* __restrict__ top_idx,
    const float* __restrict__ cls3, const float* __restrict__ obj3, const float* __restrict__ reg3,
    const float* __restrict__ cls4, const float* __restrict__ obj4, const float* __restrict__ reg4,
    const float* __restrict__ cls5, const float* __restrict__ obj5, const float* __restrict__ reg5,
    float4* __restrict__ boxes, float4* __restrict__ boxesoff,
    float* __restrict__ out_labels)
{
  int t = blockIdx.x * 256 + threadIdx.x;
  if (t >= NB * NK) return;
  int b = t / NK;
  int a = top_idx[t];
  const float *cls, *obj, *reg; int pos, HW, x, y; float stride;
  if (a < OFF4) {
    cls = cls3; obj = obj3; reg = reg3; pos = a; HW = HW3; stride = 8.0f;
    y = pos / 160; x = pos - y * 160;
  } else if (a < OFF5) {
    cls = cls4; obj = obj4; reg = reg4; pos = a - OFF4; HW = HW4; stride = 16.0f;
    y = pos / 80; x = pos - y * 80;
  } else {
    cls = cls5; obj = obj5; reg = reg5; pos = a - OFF5; HW = HW5; stride = 32.0f;
    y = pos / 40; x = pos - y * 40;
  }
  float dx = reg[(b * 4 + 0) * HW + pos];
  float dy = reg[(b * 4 + 1) * HW + pos];
  float dw = reg[(b * 4 + 2) * HW + pos];
  float dh = reg[(b * 4 + 3) * HW + pos];
  float cx = ((float)x + sigf(dx)) * stride;
  float cy = ((float)y + sigf(dy)) * stride;
  float w = expf(dw) * stride;
  float h = expf(dh) * stride;
  float x1 = cx - w * 0.5f, y1 = cy - h * 0.5f;
  float x2 = cx + w * 0.5f, y2 = cy + h * 0.5f;
  float so = sigf(obj[b * HW + pos]);
  float s0 = so * sigf(cls[(b * 2) * HW + pos]);
  float s1 = so * sigf(cls[(b * 2 + 1) * HW + pos]);
  int label = (s1 > s0) ? 1 : 0;
  float off = (float)label * 10000.0f;
  boxes[t]    = make_float4(x1, y1, x2, y2);
  boxesoff[t] = make_float4(x1 + off, y1 + off, x2 + off, y2 + off);
  out_labels[t] = (float)label;
}

// ---------------- K4: suppression bit-matrix (iou >= 0.5), padded layout -----
__global__ __launch_bounds__(256) void k_iou(
    const float4* __restrict__ boxesoff, u64* __restrict__ mask)
{
  int t = blockIdx.x * 256 + threadIdx.x;
  if (t >= NB * NK * 8) return;
  int w = t & 7;
  int bi = t >> 3;
  int b = bi / NK;
  int i = bi - b * NK;
  float4 A = boxesoff[bi];
  float areaA = (A.z - A.x) * (A.w - A.y);
  const float4* base = boxesoff + b * NK;
  int j0 = w * 64;
  int jmax = (NK - j0 < 64) ? (NK - j0) : 64;
  u64 bits = 0;
  for (int jj = 0; jj < jmax; ++jj) {
    float4 Bx = base[j0 + jj];
    float areaB = (Bx.z - Bx.x) * (Bx.w - Bx.y);
    float ix1 = fmaxf(A.x, Bx.x);
    float iy1 = fmaxf(A.y, Bx.y);
    float ix2 = fminf(A.z, Bx.z);
    float iy2 = fminf(A.w, Bx.w);
    float iw = fmaxf(ix2 - ix1, 0.0f);
    float ih = fmaxf(iy2 - iy1, 0.0f);
    float inter = iw * ih;
    float uni = areaA + areaB - inter;
    float iou = inter / (uni + 1e-7f);
    bits |= ((u64)(iou >= 0.5f)) << jj;
  }
  mask[(size_t)b * (MROWS * 8) + (size_t)i * 8 + w] = bits;
}

// ---------------- K5: chunked greedy NMS — SALU scan + shfl butterfly --------
__global__ __launch_bounds__(64) void k_nms(
    const u64* __restrict__ mask, const float* __restrict__ top_score,
    const float4* __restrict__ boxes,
    float* __restrict__ out_boxes, float* __restrict__ out_scores,
    float* __restrict__ out_keep)
{
  int b = blockIdx.x;
  int lane = threadIdx.x;
  const u64* mb = mask + (size_t)b * (MROWS * 8);

  // valid bits (wave-uniform SGPR words via ballot)
  u64 validw[8];
#pragma unroll
  for (int c = 0; c < 8; ++c) {
    int r = c * 64 + lane;
    float s = (r < NK) ? top_score[b * NK + r] : -1.0f;
    validw[c] = __ballot(s > 0.3f);
  }

  u64 supp[8] = {0, 0, 0, 0, 0, 0, 0, 0};
  u64 keepw[8];
  u64 row[2][8];

  // prefetch chunk 0 rows (lane l = row l), words 0..7
  {
    const u64* rp = mb + (size_t)lane * 8;
#pragma unroll
    for (int w = 0; w < 8; ++w) row[0][w] = rp[w];
  }

#pragma unroll
  for (int c = 0; c < 8; ++c) {
    const int cur = c & 1, nxt = cur ^ 1;
    // prefetch next chunk's rows (words c+1..7) — hidden under the scan
    if (c < 7) {
      const u64* rp = mb + (size_t)((c + 1) * 64 + lane) * 8;
#pragma unroll
      for (int w = 0; w < 8; ++w)
        if (w >= c + 1) row[nxt][w] = rp[w];
    }
    // ---- intra-chunk sequential scan: all state wave-uniform (SALU) ----
    u32 rlo = (u32)row[cur][c];
    u32 rhi = (u32)(row[cur][c] >> 32);
    u64 sw = supp[c], vw = validw[c], km = 0;
#pragma unroll 4
    for (int i = 0; i < 64; ++i) {
      // NOTE: readlane returns signed int — MUST truncate to u32 before
      // widening, else sign-extension ORs garbage into the high word.
      u64 wi = ((u64)(u32)__builtin_amdgcn_readlane(rhi, i) << 32) |
               (u64)(u32)__builtin_amdgcn_readlane(rlo, i);
      u64 bit = 1ull << i;
      if ((vw & bit) && !(sw & bit)) { sw |= wi; km |= bit; }
    }
    keepw[c] = km;
    // ---- cross-chunk suppression: OR kept rows' future words across lanes --
    u64 sel = ((km >> lane) & 1ull) ? ~0ull : 0ull;
#pragma unroll
    for (int w = c + 1; w < 8; ++w) {
      u64 v = row[cur][w] & sel;
#pragma unroll
      for (int off = 1; off < 64; off <<= 1)
        v |= (u64)__shfl_xor((unsigned long long)v, off, 64);
      supp[w] |= v;      // v uniform after butterfly
    }
  }

  // ---- finalize outputs ----
#pragma unroll
  for (int c = 0; c < 8; ++c) {
    int r = c * 64 + lane;
    if (r < NK) {
      int kp = (int)((keepw[c] >> lane) & 1ull);
      float4 bx = boxes[b * NK + r];
      float s = top_score[b * NK + r];
      float4 ob;
      ob.x = kp ? bx.x : 0.0f;
      ob.y = kp ? bx.y : 0.0f;
      ob.z = kp ? bx.z : 0.0f;
      ob.w = kp ? bx.w : 0.0f;
      reinterpret_cast<float4*>(out_boxes)[b * NK + r] = ob;
      out_scores[b * NK + r] = kp ? s : 0.0f;
      out_keep[b * NK + r]   = kp ? 1.0f : 0.0f;
    }
  }
}

// ---------------- launcher ---------------------------------------------------
extern "C" void kernel_launch(void* const* d_in, const int* in_sizes, int n_in,
                              void* d_out, int out_size, void* d_ws, size_t ws_size,
                              hipStream_t stream) {
  const float* cls3 = (const float*)d_in[0];
  const float* reg3 = (const float*)d_in[1];
  const float* obj3 = (const float*)d_in[2];
  const float* cls4 = (const float*)d_in[3];
  const float* reg4 = (const float*)d_in[4];
  const float* obj4 = (const float*)d_in[5];
  const float* cls5 = (const float*)d_in[6];
  const float* reg5 = (const float*)d_in[7];
  const float* obj5 = (const float*)d_in[8];

  char* ws = (char*)d_ws;
  u32*    keys      = (u32*)   (ws + 0);          //  8,601,600
  int*    ok        = (int*)   (ws + 8601600);    //        256
  int*    top_idx   = (int*)   (ws + 8601856);    //    128,000
  float*  top_score = (float*) (ws + 8729856);    //    128,000
  float4* boxes     = (float4*)(ws + 8857856);    //    512,000
  float4* boxesoff  = (float4*)(ws + 9369856);    //    512,000
  u64*    mask      = (u64*)   (ws + 9881856);    //  2,097,152  (end ~12.0 MB)

  float* out        = (float*)d_out;
  float* out_boxes  = out;
  float* out_scores = out + 128000;
  float* out_labels = out + 160000;
  float* out_keep   = out + 192000;

  dim3 gscore((NA4 + 255) / 256, NB);
  k_score<<<gscore, 256, 0, stream>>>(cls3, obj3, cls4, obj4, cls5, obj5, (uint4*)keys);
  k_topk<<<NB, 1024, 0, stream>>>(keys, ok, top_idx, top_score);
  k_select_fb<<<NB, 1024, 0, stream>>>(keys, ok, top_idx, top_score);
  k_decode<<<(NB * NK + 255) / 256, 256, 0, stream>>>(top_idx,
      cls3, obj3, reg3, cls4, obj4, reg4, cls5, obj5, reg5,
      boxes, boxesoff, out_labels);
  k_iou<<<(NB * NK * 8 + 255) / 256, 256, 0, stream>>>(boxesoff, mask);
  k_nms<<<NB, 64, 0, stream>>>(mask, top_score, boxes, out_boxes, out_scores, out_keep);
}

// Round 7
// 97.313 us; speedup vs baseline: 3.1261x; 1.0985x over previous
//
#include <hip/hip_runtime.h>
#include <hip/hip_bf16.h>
#include <stdint.h>

#define NB 64
#define NA 33600
#define NK 500
#define HW3 25600
#define HW4 6400
#define HW5 1600
#define OFF4 25600
#define OFF5 32000
#define NBIN 2048
#define CAP 2048
#define NA4 8400
#define MROWS 512   // padded rows per batch in mask (512*8 u64 = 32 KB/batch)

typedef unsigned int u32;
typedef unsigned long long u64;

__device__ __forceinline__ float sigf(float x) { return 1.0f / (1.0f + expf(-x)); }

__device__ __forceinline__ u32 f2key(float f) {
  u32 u = __float_as_uint(f);
  return (u & 0x80000000u) ? ~u : (u | 0x80000000u);
}
__device__ __forceinline__ float key2f(u32 k) {
  u32 u = (k & 0x80000000u) ? (k ^ 0x80000000u) : ~k;
  return __uint_as_float(u);
}
__device__ __forceinline__ int bin_of(float s) {
  int b = (int)(s * 2048.0f);
  return b > 2047 ? 2047 : b;   // monotone nondecreasing in s
}
__device__ __forceinline__ u32 mkkey(float o, float c0, float c1) {
  float so = sigf(o);
  float s = fmaxf(so * sigf(c0), so * sigf(c1));
  float masked = (s > 0.3f) ? s : -1.0f;
  return f2key(masked);
}
__device__ __forceinline__ u64 uniform64(u64 v) {
  // readfirstlane both halves -> compiler-provable wave-uniform (SGPR)
  u32 lo = (u32)__builtin_amdgcn_readfirstlane((int)(u32)v);
  u32 hi = (u32)__builtin_amdgcn_readfirstlane((int)(u32)(v >> 32));
  return ((u64)hi << 32) | lo;
}

// ---------------- K1: masked max-score -> keys (pure streaming, float4) ------
__global__ __launch_bounds__(256) void k_score(
    const float* __restrict__ cls3, const float* __restrict__ obj3,
    const float* __restrict__ cls4, const float* __restrict__ obj4,
    const float* __restrict__ cls5, const float* __restrict__ obj5,
    uint4* __restrict__ keys4)
{
  int b = blockIdx.y;
  int i4 = blockIdx.x * 256 + threadIdx.x;       // float4-granular anchor index
  if (i4 >= NA4) return;
  const float* cls; const float* obj; int p4, HW;
  if (i4 < 6400)      { cls = cls3; obj = obj3; p4 = i4;        HW = HW3; }
  else if (i4 < 8000) { cls = cls4; obj = obj4; p4 = i4 - 6400; HW = HW4; }
  else                { cls = cls5; obj = obj5; p4 = i4 - 8000; HW = HW5; }
  float4 o  = reinterpret_cast<const float4*>(obj + (size_t)b * HW)[p4];
  float4 c0 = reinterpret_cast<const float4*>(cls + (size_t)(b * 2) * HW)[p4];
  float4 c1 = reinterpret_cast<const float4*>(cls + (size_t)(b * 2 + 1) * HW)[p4];
  uint4 kv;
  kv.x = mkkey(o.x, c0.x, c1.x);
  kv.y = mkkey(o.y, c0.y, c1.y);
  kv.z = mkkey(o.z, c0.z, c1.z);
  kv.w = mkkey(o.w, c0.w, c1.w);
  keys4[(size_t)b * NA4 + i4] = kv;
}

// ---------------- K2: fused topk(+radix fallback)+decode, 1 block/batch -----
__global__ __launch_bounds__(1024) void k_topk(
    const u32* __restrict__ keys,
    const float* __restrict__ cls3, const float* __restrict__ obj3, const float* __restrict__ reg3,
    const float* __restrict__ cls4, const float* __restrict__ obj4, const float* __restrict__ reg4,
    const float* __restrict__ cls5, const float* __restrict__ obj5, const float* __restrict__ reg5,
    float* __restrict__ top_score,
    float4* __restrict__ boxes, float4* __restrict__ boxesoff,
    float* __restrict__ out_labels)
{
  int b = blockIdx.x, tid = threadIdx.x;
  __shared__ u32 hist[NBIN];
  __shared__ u32 part[256];
  __shared__ u64 cand[CAP];
  __shared__ int idx_lds[NK];
  __shared__ u32 lcnt;
  __shared__ int sh_p;
  __shared__ u32 sh_R;
  __shared__ int sh_digit;
  __shared__ u32 sh_cnt;

  for (int i = tid; i < NBIN; i += 1024) hist[i] = 0;
  if (tid < NK) idx_lds[tid] = 0;
  if (tid == 0) { lcnt = 0; }
  __syncthreads();

  const u32* kb = keys + (size_t)b * NA;
  const uint4* kb4 = reinterpret_cast<const uint4*>(kb);

  // ---- pass 1: LDS histogram of scores > 0.3 ----
  for (int i4 = tid; i4 < NA4; i4 += 1024) {
    uint4 kv = kb4[i4];
    u32 ks[4] = {kv.x, kv.y, kv.z, kv.w};
#pragma unroll
    for (int c = 0; c < 4; ++c) {
      float s = key2f(ks[c]);
      if (s > 0.3f) atomicAdd(&hist[bin_of(s)], 1u);
    }
  }
  __syncthreads();
  // ---- suffix scan over 256 groups of 8 bins -> pivot ----
  if (tid < 256) {
    u32 s8 = 0;
#pragma unroll
    for (int k = 0; k < 8; ++k) s8 += hist[tid * 8 + k];
    part[tid] = s8;
  }
  __syncthreads();
  for (int off = 1; off < 256; off <<= 1) {
    u32 add = 0;
    if (tid < 256 && tid + off < 256) add = part[tid + off];
    __syncthreads();
    if (tid < 256) part[tid] += add;
    __syncthreads();
  }
  if (tid == 0 && part[0] < NK) sh_p = -1;
  if (tid < 256) {
    u32 S = part[tid];
    u32 Snext = (tid == 255) ? 0u : part[tid + 1];
    if (S >= NK && Snext < NK) {
      u32 run = Snext;
      int p = tid * 8;
      for (int k = 7; k >= 0; --k) {
        run += hist[tid * 8 + k];
        if (run >= NK) { p = tid * 8 + k; break; }
      }
      sh_p = p;
    }
  }
  __syncthreads();
  int p = sh_p;
  bool fail = (p < 0);
  if (!fail) {
    // ---- pass 2: collect candidates with bin >= pivot into LDS ----
    for (int i4 = tid; i4 < NA4; i4 += 1024) {
      uint4 kv = kb4[i4];
      u32 ks[4] = {kv.x, kv.y, kv.z, kv.w};
#pragma unroll
      for (int c = 0; c < 4; ++c) {
        float s = key2f(ks[c]);
        if (s > 0.3f && bin_of(s) >= p) {
          u32 slot = atomicAdd(&lcnt, 1u);
          if (slot < CAP) cand[slot] = ((u64)ks[c] << 16) | (u32)(0xFFFF - (i4 * 4 + c));
        }
      }
    }
    __syncthreads();
    fail = (lcnt > CAP);
  }

  if (!fail) {
    // ---- counting-rank (distinct keys -> unique ranks), ordered top-500 ----
    int n = (int)lcnt;
    for (int t = tid; t < n; t += 1024) {
      u64 k = cand[t];
      int rank = 0;
      for (int j = 0; j < n; ++j) rank += (cand[j] > k) ? 1 : 0;
      if (rank < NK) {
        idx_lds[rank] = 0xFFFF - (int)(k & 0xFFFFull);
        top_score[b * NK + rank] = key2f((u32)(k >> 16));
      }
    }
  } else {
    // ---- inline exact 48-bit radix fallback (rare path) ----
    u64 prefix = 0, prefmask = 0;
    u32 R = NK;
    for (int pass = 0; pass < 6; ++pass) {
      int shift = 40 - 8 * pass;
      if (tid < 256) part[tid] = 0;
      __syncthreads();
      for (int i = tid; i < NA; i += 1024) {
        u64 k48 = ((u64)kb[i] << 16) | (u32)(0xFFFF - i);
        if ((k48 & prefmask) == prefix)
          atomicAdd(&part[(u32)(k48 >> shift) & 255u], 1u);
      }
      __syncthreads();
      if (tid < 256) hist[tid] = part[tid];
      __syncthreads();
      for (int off = 1; off < 256; off <<= 1) {
        u32 add = 0;
        if (tid < 256 && tid + off < 256) add = hist[tid + off];
        __syncthreads();
        if (tid < 256) hist[tid] += add;
        __syncthreads();
      }
      if (tid < 256) {
        u32 s = hist[tid];
        u32 snext = (tid == 255) ? 0u : hist[tid + 1];
        if (s >= R && snext < R) { sh_digit = tid; sh_R = R - snext; }
      }
      __syncthreads();
      prefix |= ((u64)sh_digit) << shift;
      R = sh_R;
      prefmask |= 0xFFull << shift;
      __syncthreads();
    }
    if (tid == 0) sh_cnt = 0;
    if (tid < NK) top_score[b * NK + tid] = -1.0f;   // default (exact-500 invariant makes this moot)
    __syncthreads();
    for (int i = tid; i < NA; i += 1024) {
      u64 k48 = ((u64)kb[i] << 16) | (u32)(0xFFFF - i);
      if (k48 >= prefix) {
        u32 slot = atomicAdd(&sh_cnt, 1u);
        if (slot < 512) cand[slot] = k48;
      }
    }
    __syncthreads();
    int n = (sh_cnt < (u32)NK) ? (int)sh_cnt : NK;
    for (int t = tid; t < n; t += 1024) {
      u64 k = cand[t];
      int rank = 0;
      for (int j = 0; j < n; ++j) rank += (cand[j] > k) ? 1 : 0;
      if (rank < NK) {
        idx_lds[rank] = 0xFFFF - (int)(k & 0xFFFFull);
        top_score[b * NK + rank] = key2f((u32)(k >> 16));
      }
    }
  }
  __syncthreads();

  // ---- decode phase: threads 0..499 decode the selected anchors ----
  if (tid < NK) {
    int a = idx_lds[tid];
    const float *cls, *obj, *reg; int pos, HW, x, y; float stride;
    if (a < OFF4) {
      cls = cls3; obj = obj3; reg = reg3; pos = a; HW = HW3; stride = 8.0f;
      y = pos / 160; x = pos - y * 160;
    } else if (a < OFF5) {
      cls = cls4; obj = obj4; reg = reg4; pos = a - OFF4; HW = HW4; stride = 16.0f;
      y = pos / 80; x = pos - y * 80;
    } else {
      cls = cls5; obj = obj5; reg = reg5; pos = a - OFF5; HW = HW5; stride = 32.0f;
      y = pos / 40; x = pos - y * 40;
    }
    float dx = reg[(b * 4 + 0) * HW + pos];
    float dy = reg[(b * 4 + 1) * HW + pos];
    float dw = reg[(b * 4 + 2) * HW + pos];
    float dh = reg[(b * 4 + 3) * HW + pos];
    float cx = ((float)x + sigf(dx)) * stride;
    float cy = ((float)y + sigf(dy)) * stride;
    float w = expf(dw) * stride;
    float h = expf(dh) * stride;
    float x1 = cx - w * 0.5f, y1 = cy - h * 0.5f;
    float x2 = cx + w * 0.5f, y2 = cy + h * 0.5f;
    float so = sigf(obj[b * HW + pos]);
    float s0 = so * sigf(cls[(b * 2) * HW + pos]);
    float s1 = so * sigf(cls[(b * 2 + 1) * HW + pos]);
    int label = (s1 > s0) ? 1 : 0;
    float off = (float)label * 10000.0f;
    int t = b * NK + tid;
    boxes[t]    = make_float4(x1, y1, x2, y2);
    boxesoff[t] = make_float4(x1 + off, y1 + off, x2 + off, y2 + off);
    out_labels[t] = (float)label;
  }
}

// ---------------- K3: suppression bit-matrix (iou >= 0.5), padded layout -----
__global__ __launch_bounds__(256) void k_iou(
    const float4* __restrict__ boxesoff, u64* __restrict__ mask)
{
  int t = blockIdx.x * 256 + threadIdx.x;
  if (t >= NB * NK * 8) return;
  int w = t & 7;
  int bi = t >> 3;
  int b = bi / NK;
  int i = bi - b * NK;
  float4 A = boxesoff[bi];
  float areaA = (A.z - A.x) * (A.w - A.y);
  const float4* base = boxesoff + b * NK;
  int j0 = w * 64;
  int jmax = (NK - j0 < 64) ? (NK - j0) : 64;
  u64 bits = 0;
  for (int jj = 0; jj < jmax; ++jj) {
    float4 Bx = base[j0 + jj];
    float areaB = (Bx.z - Bx.x) * (Bx.w - Bx.y);
    float ix1 = fmaxf(A.x, Bx.x);
    float iy1 = fmaxf(A.y, Bx.y);
    float ix2 = fminf(A.z, Bx.z);
    float iy2 = fminf(A.w, Bx.w);
    float iw = fmaxf(ix2 - ix1, 0.0f);
    float ih = fmaxf(iy2 - iy1, 0.0f);
    float inter = iw * ih;
    float uni = areaA + areaB - inter;
    float iou = inter / (uni + 1e-7f);
    bits |= ((u64)(iou >= 0.5f)) << jj;
  }
  mask[(size_t)b * (MROWS * 8) + (size_t)i * 8 + w] = bits;
}

// ---------------- K4: chunked greedy NMS — scalarized scan -------------------
__global__ __launch_bounds__(64) void k_nms(
    const u64* __restrict__ mask, const float* __restrict__ top_score,
    const float4* __restrict__ boxes,
    float* __restrict__ out_boxes, float* __restrict__ out_scores,
    float* __restrict__ out_keep)
{
  int b = blockIdx.x;
  int lane = threadIdx.x;
  const u64* mb = mask + (size_t)b * (MROWS * 8);

  // valid bits (wave-uniform via ballot)
  u64 validw[8];
#pragma unroll
  for (int c = 0; c < 8; ++c) {
    int r = c * 64 + lane;
    float s = (r < NK) ? top_score[b * NK + r] : -1.0f;
    validw[c] = __ballot(s > 0.3f);
  }

  u64 supp[8] = {0, 0, 0, 0, 0, 0, 0, 0};   // kept wave-uniform (SGPR) below
  u64 keepw[8];
  u64 row[2][8];

  // prefetch chunk 0 rows (lane l = row l), words 0..7
  {
    const u64* rp = mb + (size_t)lane * 8;
#pragma unroll
    for (int w = 0; w < 8; ++w) row[0][w] = rp[w];
  }

#pragma unroll
  for (int c = 0; c < 8; ++c) {
    const int cur = c & 1, nxt = cur ^ 1;
    // prefetch next chunk's rows (words c+1..7) — hidden under the scan
    if (c < 7) {
      const u64* rp = mb + (size_t)((c + 1) * 64 + lane) * 8;
#pragma unroll
      for (int w = 0; w < 8; ++w)
        if (w >= c + 1) row[nxt][w] = rp[w];
    }
    // ---- intra-chunk sequential scan: all state wave-uniform (SALU) ----
    u32 rlo = (u32)row[cur][c];
    u32 rhi = (u32)(row[cur][c] >> 32);
    u64 sw = supp[c], vw = validw[c], km = 0;
#pragma unroll
    for (int i = 0; i < 64; ++i) {
      // readlane returns signed int — truncate to u32 before widening.
      u64 wi = ((u64)(u32)__builtin_amdgcn_readlane(rhi, i) << 32) |
               (u64)(u32)__builtin_amdgcn_readlane(rlo, i);
      u64 bit = 1ull << i;
      if ((vw & bit) && !(sw & bit)) { sw |= wi; km |= bit; }
    }
    keepw[c] = km;
    // ---- cross-chunk suppression: OR kept rows' future words across lanes --
    u64 sel = ((km >> lane) & 1ull) ? ~0ull : 0ull;
#pragma unroll
    for (int w = c + 1; w < 8; ++w) {
      u64 v = row[cur][w] & sel;
#pragma unroll
      for (int off = 1; off < 64; off <<= 1)
        v |= (u64)__shfl_xor((unsigned long long)v, off, 64);
      supp[w] |= uniform64(v);   // force back to SGPR so the next scan is SALU
    }
  }

  // ---- finalize outputs ----
#pragma unroll
  for (int c = 0; c < 8; ++c) {
    int r = c * 64 + lane;
    if (r < NK) {
      int kp = (int)((keepw[c] >> lane) & 1ull);
      float4 bx = boxes[b * NK + r];
      float s = top_score[b * NK + r];
      float4 ob;
      ob.x = kp ? bx.x : 0.0f;
      ob.y = kp ? bx.y : 0.0f;
      ob.z = kp ? bx.z : 0.0f;
      ob.w = kp ? bx.w : 0.0f;
      reinterpret_cast<float4*>(out_boxes)[b * NK + r] = ob;
      out_scores[b * NK + r] = kp ? s : 0.0f;
      out_keep[b * NK + r]   = kp ? 1.0f : 0.0f;
    }
  }
}

// ---------------- launcher ---------------------------------------------------
extern "C" void kernel_launch(void* const* d_in, const int* in_sizes, int n_in,
                              void* d_out, int out_size, void* d_ws, size_t ws_size,
                              hipStream_t stream) {
  const float* cls3 = (const float*)d_in[0];
  const float* reg3 = (const float*)d_in[1];
  const float* obj3 = (const float*)d_in[2];
  const float* cls4 = (const float*)d_in[3];
  const float* reg4 = (const float*)d_in[4];
  const float* obj4 = (const float*)d_in[5];
  const float* cls5 = (const float*)d_in[6];
  const float* reg5 = (const float*)d_in[7];
  const float* obj5 = (const float*)d_in[8];

  char* ws = (char*)d_ws;
  u32*    keys      = (u32*)   (ws + 0);          //  8,601,600
  float*  top_score = (float*) (ws + 8601600);    //    128,000
  float4* boxes     = (float4*)(ws + 8729600);    //    512,000
  float4* boxesoff  = (float4*)(ws + 9241600);    //    512,000
  u64*    mask      = (u64*)   (ws + 9753600);    //  2,097,152  (end ~11.9 MB)

  float* out        = (float*)d_out;
  float* out_boxes  = out;
  float* out_scores = out + 128000;
  float* out_labels = out + 160000;
  float* out_keep   = out + 192000;

  dim3 gscore((NA4 + 255) / 256, NB);
  k_score<<<gscore, 256, 0, stream>>>(cls3, obj3, cls4, obj4, cls5, obj5, (uint4*)keys);
  k_topk<<<NB, 1024, 0, stream>>>(keys,
      cls3, obj3, reg3, cls4, obj4, reg4, cls5, obj5, reg5,
      top_score, boxes, boxesoff, out_labels);
  k_iou<<<(NB * NK * 8 + 255) / 256, 256, 0, stream>>>(boxesoff, mask);
  k_nms<<<NB, 64, 0, stream>>>(mask, top_score, boxes, out_boxes, out_scores, out_keep);
}